// Round 5
// baseline (12154.976 us; speedup 1.0000x reference)
//
#include <hip/hip_runtime.h>
#include <stdint.h>
#include <math.h>

// Bayesian STDP persistent-scan kernel, v5.
// v4 -> v5:
//  - __launch_bounds__(1024,4): 128-VGPR budget (v4's bare bound forced 64,
//    sinking the spikes prefetch to its use site).
//  - GEMM1 col-sliced: wave w owns cols [32w,32w+32), lane=row. W chunks via
//    same-address LDS broadcast (W traffic 128KB->8KB/step), psp read once,
//    partials combined via LDS buffer part[16][64][4] (no shfl reductions).
//  - Phase D/E row mapping b=4r+dbh (removes provable 4-way bank conflict).
//  - psp update overlapped with the grid-barrier window (flag store -> update
//    -> poll), psp columns for post_pre prefetched to registers beforehand.

#define TSTEPS 1000
#define BB     64
#define NINF   512
#define NOUTT  128
#define NG     32
#define NO     4
#define NTHR   1024
#define PSPD   0.9f
#define VD     0.9f
#define LRC    1e-3f
#define PS     516                  // padded psp/W row stride (floats)

#define FLAGS_OFF (2*NG*BB*2)       // stats floats before flags

__device__ __forceinline__ void sync_lds() {
  // barrier draining only LDS (lgkmcnt=0, vmcnt=63, expcnt=7)
  asm volatile("" ::: "memory");
  __builtin_amdgcn_s_waitcnt(0xC07F);
  __builtin_amdgcn_s_barrier();
  asm volatile("" ::: "memory");
}

__device__ __forceinline__ float2 aload_f2(const float* p) {
  unsigned long long u = __hip_atomic_load((const unsigned long long*)p,
      __ATOMIC_RELAXED, __HIP_MEMORY_SCOPE_AGENT);
  float2 r;
  r.x = __uint_as_float((unsigned)u);
  r.y = __uint_as_float((unsigned)(u >> 32));
  return r;
}
__device__ __forceinline__ void astore_f2(float* p, float x, float y) {
  unsigned long long u = (unsigned long long)__float_as_uint(x)
                       | ((unsigned long long)__float_as_uint(y) << 32);
  __hip_atomic_store((unsigned long long*)p, u, __ATOMIC_RELAXED, __HIP_MEMORY_SCOPE_AGENT);
}
__device__ __forceinline__ void astore_i(int* p, int v) {
  __hip_atomic_store(p, v, __ATOMIC_RELAXED, __HIP_MEMORY_SCOPE_AGENT);
}
__device__ __forceinline__ int aload_i(const int* p) {
  return __hip_atomic_load(p, __ATOMIC_RELAXED, __HIP_MEMORY_SCOPE_AGENT);
}

__global__ __launch_bounds__(NTHR, 4)
void bstdp_kernel(const float* __restrict__ spikes,   // [T][B][NIN]
                  const float* __restrict__ weight,   // [NOUT][NIN]
                  const float* __restrict__ bias,     // [NOUT]
                  float* __restrict__ out,            // [T][B][NOUT] ++ [B][NOUT]
                  float* __restrict__ ws)
{
  const int g   = blockIdx.x;
  const int tid = threadIdx.x;

  float* stats = ws;                       // [2][NG][BB][2] floats
  int*   flags = (int*)(ws + FLAGS_OFF);   // [NG][32] ints (poison 0xAA.. < 1)

  __shared__ __align__(16) float psp[BB*PS];     // 132 KB replicated psp trace
  __shared__ __align__(16) float Wt[NO*PS];      // 8.25 KB W tile
  __shared__ __align__(16) float part[16*BB*NO]; // 16 KB GEMM1 partials [w][row][o]
  __shared__ __align__(16) float uS[NO*BB];      // membrane [o][row]
  __shared__ __align__(16) float zT[BB*NO];      // z [row][o]
  __shared__ float pmS[16];                      // per-wave pm partials [w][o]
  __shared__ float btS[NO];

  // ---- prologue ----
  #pragma unroll
  for (int e = tid; e < NO*NINF; e += NTHR)
    Wt[(e>>9)*PS + (e&511)] = weight[g*(NO*NINF) + e];
  if (tid < NO)    btS[tid] = bias[g*NO + tid];
  if (tid < NO*BB) uS[tid] = 0.0f;
  #pragma unroll
  for (int k = 0; k < 8; ++k) {
    int j = tid*4 + k*4096;
    *(float4*)&psp[(j>>9)*PS + (j&511)] = *(const float4*)(spikes + j);
  }
  __syncthreads();

  const int w16 = tid >> 6;        // wave id 0..15
  const int row = tid & 63;        // GEMM1: batch row
  const int cs  = w16 * 32;        // GEMM1: col slice start
  const int q4  = tid & 3;         // phase D: o-subgroup
  const int b4  = tid >> 2;        // phase D: batch row (tid<256)
  const int dbh = tid & 3;         // phase E: row residue / owned o
  const int di  = (tid >> 2) * 2;  // phase E: column pair

  for (int t = 0; t < TSTEPS; ++t) {
    const int sb = t & 1;

    // ---------- A: spikes(t+1) prefetch + col-sliced GEMM1 partials ----------
    float4 spn[8];
    if (t + 1 < TSTEPS) {
      const float* sp = spikes + (size_t)(t+1)*(BB*NINF) + tid*4;
      #pragma unroll
      for (int k = 0; k < 8; ++k) spn[k] = *(const float4*)(sp + k*4096);
    }
    {
      float a0 = 0.f, a1 = 0.f, a2 = 0.f, a3 = 0.f;
      const float* pr = &psp[row*PS + cs];
      #pragma unroll
      for (int k = 0; k < 8; ++k) {
        float4 p = *(const float4*)(pr + 4*k);
        float4 W0 = *(const float4*)(&Wt[0*PS + cs + 4*k]);   // broadcast
        float4 W1 = *(const float4*)(&Wt[1*PS + cs + 4*k]);
        float4 W2 = *(const float4*)(&Wt[2*PS + cs + 4*k]);
        float4 W3 = *(const float4*)(&Wt[3*PS + cs + 4*k]);
        a0 = fmaf(p.x,W0.x, fmaf(p.y,W0.y, fmaf(p.z,W0.z, fmaf(p.w,W0.w, a0))));
        a1 = fmaf(p.x,W1.x, fmaf(p.y,W1.y, fmaf(p.z,W1.z, fmaf(p.w,W1.w, a1))));
        a2 = fmaf(p.x,W2.x, fmaf(p.y,W2.y, fmaf(p.z,W2.z, fmaf(p.w,W2.w, a2))));
        a3 = fmaf(p.x,W3.x, fmaf(p.y,W3.y, fmaf(p.z,W3.z, fmaf(p.w,W3.w, a3))));
      }
      *(float4*)&part[(w16*BB + row)*NO] = make_float4(a0, a1, a2, a3);
    }
    sync_lds();

    // ---------- B: Dp register prefetch; partial-reduce -> u, stats ----------
    float2 Dp[16];
    #pragma unroll
    for (int r = 0; r < 16; ++r)
      Dp[r] = *(const float2*)&psp[(4*r + dbh)*PS + di];

    if (tid < 256) {
      // part[w][row][o] at w*256 + tid  (tid = row*4+o)
      float s = 0.f;
      #pragma unroll
      for (int k = 0; k < 16; ++k) s += part[k*256 + tid];
      const int ro = tid >> 2, oo = tid & 3;
      float u = VD*uS[oo*BB + ro] + s + btS[oo];
      uS[oo*BB + ro] = u;
      // quad stats (max, sumexp over the 4 o-lanes of this row)
      float mx = u;
      mx = fmaxf(mx, __shfl_xor(mx, 1));
      mx = fmaxf(mx, __shfl_xor(mx, 2));
      float ss = expf(u - mx);
      ss += __shfl_xor(ss, 1);
      ss += __shfl_xor(ss, 2);
      if (oo == 0)
        astore_f2(stats + ((size_t)(sb*NG + g)*BB + ro)*2, mx, ss);
    }
    __syncthreads();                       // drains stats stores + spn loads
    if (tid == 0) astore_i(&flags[g*32], t + 1);

    // ---------- C0: psp recurrence overlapped with barrier ----------
    if (t + 1 < TSTEPS) {
      #pragma unroll
      for (int k = 0; k < 8; ++k) {
        int j = tid*4 + k*4096;
        float* pa = &psp[(j>>9)*PS + (j&511)];
        float4 p = *(float4*)pa;
        p.x = PSPD*p.x + spn[k].x;
        p.y = PSPD*p.y + spn[k].y;
        p.z = PSPD*p.z + spn[k].z;
        p.w = PSPD*p.w + spn[k].w;
        *(float4*)pa = p;
      }
    }
    if (tid < 64) {
      const int target = t + 1;
      for (;;) {
        int v = (tid < NG) ? aload_i(&flags[tid*32]) : 0x7fffffff;
        if (~__ballot(v >= target) == 0ULL) break;
        __builtin_amdgcn_s_sleep(1);
      }
    }
    sync_lds();

    // ---------- D: merge stats, z, out store, pm partials ----------
    if (tid < 256) {
      float M = -1e30f, S = 0.f;
      #pragma unroll
      for (int k = 0; k < 8; ++k) {
        int gg = q4*8 + k;
        float2 msv = aload_f2(stats + ((size_t)(sb*NG + gg)*BB + b4)*2);
        float Mn = fmaxf(M, msv.x);
        S = S*expf(M - Mn) + msv.y*expf(msv.x - Mn);
        M = Mn;
      }
      #pragma unroll
      for (int m = 1; m < 4; m <<= 1) {
        float Mo = __shfl_xor(M, m);
        float So = __shfl_xor(S, m);
        float Mn = fmaxf(M, Mo);
        S = S*expf(M - Mn) + So*expf(Mo - Mn);
        M = Mn;
      }
      float z = expf(uS[q4*BB + b4] - M) / S;
      zT[b4*NO + q4] = z;
      __builtin_nontemporal_store(z,
          out + (size_t)t*(BB*NOUTT) + (size_t)b4*NOUTT + g*NO + q4);
      float v = z;
      #pragma unroll
      for (int m = 4; m < 64; m <<= 1) v += __shfl_xor(v, m);
      if ((tid & 63) < 4) pmS[(tid >> 6)*NO + q4] = v;
    }
    sync_lds();

    // ---------- E: post_pre from Dp regs + W,b update ----------
    {
      float pp[NO][2] = {};
      #pragma unroll
      for (int r = 0; r < 16; ++r) {
        int b = 4*r + dbh;
        float4 z4 = *(const float4*)&zT[b*NO];   // broadcast across quads
        float2 pv = Dp[r];
        pp[0][0] = fmaf(z4.x, pv.x, pp[0][0]); pp[0][1] = fmaf(z4.x, pv.y, pp[0][1]);
        pp[1][0] = fmaf(z4.y, pv.x, pp[1][0]); pp[1][1] = fmaf(z4.y, pv.y, pp[1][1]);
        pp[2][0] = fmaf(z4.z, pv.x, pp[2][0]); pp[2][1] = fmaf(z4.z, pv.y, pp[2][1]);
        pp[3][0] = fmaf(z4.w, pv.x, pp[3][0]); pp[3][1] = fmaf(z4.w, pv.y, pp[3][1]);
      }
      #pragma unroll
      for (int m = 1; m < 4; m <<= 1) {
        #pragma unroll
        for (int o = 0; o < NO; ++o) {
          pp[o][0] += __shfl_xor(pp[o][0], m);
          pp[o][1] += __shfl_xor(pp[o][1], m);
        }
      }
      float ppx, ppy;
      switch (dbh) {
        case 0:  ppx = pp[0][0]; ppy = pp[0][1]; break;
        case 1:  ppx = pp[1][0]; ppy = pp[1][1]; break;
        case 2:  ppx = pp[2][0]; ppy = pp[2][1]; break;
        default: ppx = pp[3][0]; ppy = pp[3][1]; break;
      }
      float pm = (pmS[dbh] + pmS[NO+dbh] + pmS[2*NO+dbh] + pmS[3*NO+dbh]) * (1.0f/BB);
      float* wp = &Wt[dbh*PS + di];
      float w0 = wp[0], w1 = wp[1];
      wp[0] = w0 + LRC*(expf(-w0)*ppx*(1.0f/BB) - pm);
      wp[1] = w1 + LRC*(expf(-w1)*ppy*(1.0f/BB) - pm);
      if (tid < NO) {
        float pmb = (pmS[tid] + pmS[NO+tid] + pmS[2*NO+tid] + pmS[3*NO+tid]) * (1.0f/BB);
        float bv = btS[tid];
        btS[tid] = bv + LRC*(expf(-bv) - 1.0f)*pmb;
      }
    }
    sync_lds();
  }

  // ---- epilogue: u_final ----
  if (tid < 256) {
    __builtin_nontemporal_store(uS[q4*BB + b4],
        out + (size_t)TSTEPS*(BB*NOUTT) + (size_t)b4*NOUTT + g*NO + q4);
  }
}

extern "C" void kernel_launch(void* const* d_in, const int* in_sizes, int n_in,
                              void* d_out, int out_size, void* d_ws, size_t ws_size,
                              hipStream_t stream) {
  const float* spikes = (const float*)d_in[0];   // [1000,64,512] fp32
  const float* weight = (const float*)d_in[1];   // [128,512] fp32
  const float* bias   = (const float*)d_in[2];   // [128] fp32
  float* out = (float*)d_out;                    // [1000*64*128] ++ [64*128]
  float* ws  = (float*)d_ws;

  bstdp_kernel<<<dim3(NG), dim3(NTHR), 0, stream>>>(spikes, weight, bias, out, ws);
}